// Round 1
// baseline (2760.606 us; speedup 1.0000x reference)
//
#include <hip/hip_runtime.h>

#define EMB 64

// Concat user+item embeddings into emb buffer and initialize accumulator.
__global__ void lgcn_init(const float4* __restrict__ ue, const float4* __restrict__ ie,
                          float4* __restrict__ emb, float4* __restrict__ acc,
                          long nu4, long ni4) {
    long total = nu4 + ni4;
    long stride = (long)gridDim.x * blockDim.x;
    for (long i = (long)blockIdx.x * blockDim.x + threadIdx.x; i < total; i += stride) {
        float4 v = (i < nu4) ? ue[i] : ie[i - nu4];
        emb[i] = v;
        acc[i] = v;
    }
}

// One 64-lane wave per edge; lane = embedding dim.
// y[rows[e]][lane] += vals[e] * x[cols[e]][lane]
__global__ void lgcn_spmm(const float* __restrict__ vals, const int* __restrict__ rows,
                          const int* __restrict__ cols, const float* __restrict__ x,
                          float* __restrict__ y, int ne) {
    long gid = (long)blockIdx.x * blockDim.x + threadIdx.x;
    int e = (int)(gid >> 6);
    int lane = (int)(gid & 63);
    if (e >= ne) return;
    int r = rows[e];
    int c = cols[e];
    float v = vals[e];
    float xv = x[(size_t)c * EMB + lane];
    atomicAdd(&y[(size_t)r * EMB + lane], v * xv);
}

// acc = (acc + src) * scale   (scale=1 for layers 0,1; 0.25 fused on the last)
__global__ void lgcn_acc(const float4* __restrict__ src, float4* __restrict__ acc,
                         long n4, float scale) {
    long stride = (long)gridDim.x * blockDim.x;
    for (long i = (long)blockIdx.x * blockDim.x + threadIdx.x; i < n4; i += stride) {
        float4 a = acc[i];
        float4 s = src[i];
        a.x = (a.x + s.x) * scale;
        a.y = (a.y + s.y) * scale;
        a.z = (a.z + s.z) * scale;
        a.w = (a.w + s.w) * scale;
        acc[i] = a;
    }
}

extern "C" void kernel_launch(void* const* d_in, const int* in_sizes, int n_in,
                              void* d_out, int out_size, void* d_ws, size_t ws_size,
                              hipStream_t stream) {
    const float* ue   = (const float*)d_in[0];
    const float* ie   = (const float*)d_in[1];
    const float* vals = (const float*)d_in[2];
    const int*   rows = (const int*)d_in[3];
    const int*   cols = (const int*)d_in[4];

    const int nu = in_sizes[0] / EMB;
    const int ni = in_sizes[1] / EMB;
    const int ne = in_sizes[2];
    const long n = (long)nu + ni;
    const size_t buf_bytes = (size_t)n * EMB * sizeof(float);

    float* acc  = (float*)d_out;
    float* buf0 = (float*)d_ws;
    float* buf1 = (float*)((char*)d_ws + buf_bytes);

    const long n4  = n * (EMB / 4);
    const long nu4 = (long)nu * (EMB / 4);
    const long ni4 = (long)ni * (EMB / 4);

    lgcn_init<<<2048, 256, 0, stream>>>((const float4*)ue, (const float4*)ie,
                                        (float4*)buf0, (float4*)acc, nu4, ni4);

    float* cur = buf0;
    float* nxt = buf1;
    for (int l = 0; l < 3; ++l) {
        hipMemsetAsync(nxt, 0, buf_bytes, stream);
        long threads = (long)ne * 64;
        int blocks = (int)((threads + 255) / 256);
        lgcn_spmm<<<blocks, 256, 0, stream>>>(vals, rows, cols, cur, nxt, ne);
        float scale = (l == 2) ? 0.25f : 1.0f;
        lgcn_acc<<<2048, 256, 0, stream>>>((const float4*)nxt, (float4*)acc, n4, scale);
        float* t = cur; cur = nxt; nxt = t;
    }
}

// Round 2
// 1616.011 us; speedup vs baseline: 1.7083x; 1.7083x over previous
//
#include <hip/hip_runtime.h>

#define EMB 64
#define SCAN_TPB 256
#define SCAN_EPT 8
#define SCAN_ELEMS (SCAN_TPB * SCAN_EPT)  // 2048

// ---------- shared: init (concat embeddings -> emb buffer, acc) ----------
__global__ void lgcn_init(const float4* __restrict__ ue, const float4* __restrict__ ie,
                          float4* __restrict__ emb, float4* __restrict__ acc,
                          long nu4, long ni4) {
    long total = nu4 + ni4;
    long stride = (long)gridDim.x * blockDim.x;
    for (long i = (long)blockIdx.x * blockDim.x + threadIdx.x; i < total; i += stride) {
        float4 v = (i < nu4) ? ue[i] : ie[i - nu4];
        emb[i] = v;
        acc[i] = v;
    }
}

// ---------- CSR build ----------
__global__ void k_hist(const int* __restrict__ rows, int* __restrict__ cnt, int ne) {
    int stride = gridDim.x * blockDim.x;
    for (int e = blockIdx.x * blockDim.x + threadIdx.x; e < ne; e += stride)
        atomicAdd(&cnt[rows[e]], 1);
}

__global__ void k_scan1(const int* __restrict__ in, int* __restrict__ excl,
                        int* __restrict__ bsums, int n) {
    __shared__ int sh[SCAN_TPB];
    int t = threadIdx.x;
    int base = blockIdx.x * SCAN_ELEMS + t * SCAN_EPT;
    int v[SCAN_EPT];
    int ts = 0;
#pragma unroll
    for (int k = 0; k < SCAN_EPT; ++k) {
        v[k] = (base + k < n) ? in[base + k] : 0;
        ts += v[k];
    }
    sh[t] = ts;
    __syncthreads();
    for (int off = 1; off < SCAN_TPB; off <<= 1) {
        int x = (t >= off) ? sh[t - off] : 0;
        __syncthreads();
        sh[t] += x;
        __syncthreads();
    }
    int run = sh[t] - ts;  // exclusive prefix of this thread within block
#pragma unroll
    for (int k = 0; k < SCAN_EPT; ++k) {
        if (base + k < n) excl[base + k] = run;
        run += v[k];
    }
    if (t == SCAN_TPB - 1) bsums[blockIdx.x] = sh[t];
}

__global__ void k_scan2(const int* __restrict__ bsums, int* __restrict__ bexcl, int nb) {
    __shared__ int sh[SCAN_TPB];
    int t = threadIdx.x;
    int ts = (t < nb) ? bsums[t] : 0;
    sh[t] = ts;
    __syncthreads();
    for (int off = 1; off < SCAN_TPB; off <<= 1) {
        int x = (t >= off) ? sh[t - off] : 0;
        __syncthreads();
        sh[t] += x;
        __syncthreads();
    }
    if (t < nb) bexcl[t] = sh[t] - ts;
}

__global__ void k_scan3(int* __restrict__ row_start, int* __restrict__ cursor,
                        const int* __restrict__ bexcl, int n, int ne) {
    int base = blockIdx.x * SCAN_ELEMS + threadIdx.x * SCAN_EPT;
    int off = bexcl[blockIdx.x];
#pragma unroll
    for (int k = 0; k < SCAN_EPT; ++k) {
        if (base + k < n) {
            int v = row_start[base + k] + off;
            row_start[base + k] = v;
            cursor[base + k] = v;
        }
    }
    if (blockIdx.x == 0 && threadIdx.x == 0) row_start[n] = ne;
}

__global__ void k_scatter(const int* __restrict__ rows, const int* __restrict__ cols,
                          const float* __restrict__ vals, int* __restrict__ cursor,
                          int* __restrict__ scols, float* __restrict__ svals, int ne) {
    int stride = gridDim.x * blockDim.x;
    for (int e = blockIdx.x * blockDim.x + threadIdx.x; e < ne; e += stride) {
        int r = rows[e];
        int p = atomicAdd(&cursor[r], 1);
        scols[p] = cols[e];
        svals[p] = vals[e];
    }
}

// ---------- CSR SpMM: one wave per row, lane = dim; fused acc update ----------
__global__ void k_spmm_csr(const int* __restrict__ row_start, const int* __restrict__ scols,
                           const float* __restrict__ svals, const float* __restrict__ x,
                           float* __restrict__ nxt, float* __restrict__ acc,
                           int n, int last) {
    int wid = (int)(((long)blockIdx.x * blockDim.x + threadIdx.x) >> 6);
    int lane = threadIdx.x & 63;
    if (wid >= n) return;
    int s = row_start[wid];
    int e = row_start[wid + 1];
    float sum = 0.f;
    for (int j = s; j < e; ++j) {
        int c = scols[j];
        float v = svals[j];
        sum += v * x[(size_t)c * EMB + lane];
    }
    size_t o = (size_t)wid * EMB + lane;
    if (!last) nxt[o] = sum;
    float a = acc[o] + sum;
    if (last) a *= 0.25f;
    acc[o] = a;
}

// ---------- fallback (R1 atomic path) ----------
__global__ void lgcn_spmm_atomic(const float* __restrict__ vals, const int* __restrict__ rows,
                                 const int* __restrict__ cols, const float* __restrict__ x,
                                 float* __restrict__ y, int ne) {
    long gid = (long)blockIdx.x * blockDim.x + threadIdx.x;
    int e = (int)(gid >> 6);
    int lane = (int)(gid & 63);
    if (e >= ne) return;
    float xv = x[(size_t)cols[e] * EMB + lane];
    atomicAdd(&y[(size_t)rows[e] * EMB + lane], vals[e] * xv);
}

__global__ void lgcn_acc(const float4* __restrict__ src, float4* __restrict__ acc,
                         long n4, float scale) {
    long stride = (long)gridDim.x * blockDim.x;
    for (long i = (long)blockIdx.x * blockDim.x + threadIdx.x; i < n4; i += stride) {
        float4 a = acc[i];
        float4 s = src[i];
        a.x = (a.x + s.x) * scale;
        a.y = (a.y + s.y) * scale;
        a.z = (a.z + s.z) * scale;
        a.w = (a.w + s.w) * scale;
        acc[i] = a;
    }
}

extern "C" void kernel_launch(void* const* d_in, const int* in_sizes, int n_in,
                              void* d_out, int out_size, void* d_ws, size_t ws_size,
                              hipStream_t stream) {
    const float* ue   = (const float*)d_in[0];
    const float* ie   = (const float*)d_in[1];
    const float* vals = (const float*)d_in[2];
    const int*   rows = (const int*)d_in[3];
    const int*   cols = (const int*)d_in[4];

    const int nu = in_sizes[0] / EMB;
    const int ni = in_sizes[1] / EMB;
    const int ne = in_sizes[2];
    const long n = (long)nu + ni;
    const size_t buf_bytes = (size_t)n * EMB * sizeof(float);

    float* acc  = (float*)d_out;
    const long n4  = n * (EMB / 4);
    const long nu4 = (long)nu * (EMB / 4);
    const long ni4 = (long)ni * (EMB / 4);

    // workspace carve
    char* p = (char*)d_ws;
    float* buf0 = (float*)p;               p += buf_bytes;
    float* buf1 = (float*)p;               p += buf_bytes;
    int*   scols = (int*)p;                p += (size_t)ne * sizeof(int);
    float* svals = (float*)p;              p += (size_t)ne * sizeof(float);
    int*   row_start = (int*)p;            p += (size_t)(n + 1) * sizeof(int);
    int*   cursor = (int*)p;               p += (size_t)n * sizeof(int);
    int nb = (int)((n + SCAN_ELEMS - 1) / SCAN_ELEMS);
    int*   bsums = (int*)p;                p += (size_t)nb * sizeof(int);
    int*   bexcl = (int*)p;                p += (size_t)nb * sizeof(int);
    size_t needed = (size_t)(p - (char*)d_ws);

    if (needed <= ws_size && nb <= SCAN_TPB) {
        // ---- CSR path ----
        hipMemsetAsync(cursor, 0, (size_t)n * sizeof(int), stream);
        k_hist<<<1024, 256, 0, stream>>>(rows, cursor, ne);
        k_scan1<<<nb, SCAN_TPB, 0, stream>>>(cursor, row_start, bsums, (int)n);
        k_scan2<<<1, SCAN_TPB, 0, stream>>>(bsums, bexcl, nb);
        k_scan3<<<nb, SCAN_TPB, 0, stream>>>(row_start, cursor, bexcl, (int)n, ne);
        k_scatter<<<1024, 256, 0, stream>>>(rows, cols, vals, cursor, scols, svals, ne);

        lgcn_init<<<2048, 256, 0, stream>>>((const float4*)ue, (const float4*)ie,
                                            (float4*)buf0, (float4*)acc, nu4, ni4);

        float* cur = buf0;
        float* nxt = buf1;
        int blocks = (int)((n * 64 + 255) / 256);
        for (int l = 0; l < 3; ++l) {
            k_spmm_csr<<<blocks, 256, 0, stream>>>(row_start, scols, svals, cur, nxt, acc,
                                                   (int)n, (l == 2) ? 1 : 0);
            float* t = cur; cur = nxt; nxt = t;
        }
    } else {
        // ---- fallback: R1 atomic path ----
        lgcn_init<<<2048, 256, 0, stream>>>((const float4*)ue, (const float4*)ie,
                                            (float4*)buf0, (float4*)acc, nu4, ni4);
        float* cur = buf0;
        float* nxt = buf1;
        for (int l = 0; l < 3; ++l) {
            hipMemsetAsync(nxt, 0, buf_bytes, stream);
            long threads = (long)ne * 64;
            int blocks = (int)((threads + 255) / 256);
            lgcn_spmm_atomic<<<blocks, 256, 0, stream>>>(vals, rows, cols, cur, nxt, ne);
            float scale = (l == 2) ? 0.25f : 1.0f;
            lgcn_acc<<<2048, 256, 0, stream>>>((const float4*)nxt, (float4*)acc, n4, scale);
            float* t = cur; cur = nxt; nxt = t;
        }
    }
}

// Round 3
// 1007.908 us; speedup vs baseline: 2.7389x; 1.6033x over previous
//
#include <hip/hip_runtime.h>

#define EMB 64
#define SCAN_TPB 256
#define SCAN_EPT 8
#define SCAN_ELEMS (SCAN_TPB * SCAN_EPT)  // 2048

struct Edge { int c; float v; };  // packed 8B: one random store in scatter, one stream in spmm

// ---------- CSR build ----------
__global__ void k_hist(const int* __restrict__ rows, int* __restrict__ cnt, int ne) {
    int stride = gridDim.x * blockDim.x;
    for (int e = blockIdx.x * blockDim.x + threadIdx.x; e < ne; e += stride)
        atomicAdd(&cnt[rows[e]], 1);
}

__global__ void k_scan1(const int* __restrict__ in, int* __restrict__ excl,
                        int* __restrict__ bsums, int n) {
    __shared__ int sh[SCAN_TPB];
    int t = threadIdx.x;
    int base = blockIdx.x * SCAN_ELEMS + t * SCAN_EPT;
    int v[SCAN_EPT];
    int ts = 0;
#pragma unroll
    for (int k = 0; k < SCAN_EPT; ++k) {
        v[k] = (base + k < n) ? in[base + k] : 0;
        ts += v[k];
    }
    sh[t] = ts;
    __syncthreads();
    for (int off = 1; off < SCAN_TPB; off <<= 1) {
        int x = (t >= off) ? sh[t - off] : 0;
        __syncthreads();
        sh[t] += x;
        __syncthreads();
    }
    int run = sh[t] - ts;
#pragma unroll
    for (int k = 0; k < SCAN_EPT; ++k) {
        if (base + k < n) excl[base + k] = run;
        run += v[k];
    }
    if (t == SCAN_TPB - 1) bsums[blockIdx.x] = sh[t];
}

__global__ void k_scan2(const int* __restrict__ bsums, int* __restrict__ bexcl, int nb) {
    __shared__ int sh[SCAN_TPB];
    int t = threadIdx.x;
    int ts = (t < nb) ? bsums[t] : 0;
    sh[t] = ts;
    __syncthreads();
    for (int off = 1; off < SCAN_TPB; off <<= 1) {
        int x = (t >= off) ? sh[t - off] : 0;
        __syncthreads();
        sh[t] += x;
        __syncthreads();
    }
    if (t < nb) bexcl[t] = sh[t] - ts;
}

__global__ void k_scan3(int* __restrict__ row_start, int* __restrict__ cursor,
                        const int* __restrict__ bexcl, int n, int ne) {
    int base = blockIdx.x * SCAN_ELEMS + threadIdx.x * SCAN_EPT;
    int off = bexcl[blockIdx.x];
#pragma unroll
    for (int k = 0; k < SCAN_EPT; ++k) {
        if (base + k < n) {
            int v = row_start[base + k] + off;
            row_start[base + k] = v;
            cursor[base + k] = v;
        }
    }
    if (blockIdx.x == 0 && threadIdx.x == 0) row_start[n] = ne;
}

__global__ void k_scatter(const int* __restrict__ rows, const int* __restrict__ cols,
                          const float* __restrict__ vals, int* __restrict__ cursor,
                          Edge* __restrict__ ecv, int ne) {
    int stride = gridDim.x * blockDim.x;
    for (int e = blockIdx.x * blockDim.x + threadIdx.x; e < ne; e += stride) {
        int r = rows[e];
        int p = atomicAdd(&cursor[r], 1);
        Edge ed; ed.c = cols[e]; ed.v = vals[e];
        ecv[p] = ed;
    }
}

// ---------- CSR SpMM: one wave per row, lane = dim, 4-way ILP unroll ----------
__device__ __forceinline__ float gath0(const float* __restrict__ ue, const float* __restrict__ ie,
                                       int nu, int c, int lane) {
    const float* p = (c < nu) ? (ue + (size_t)c * EMB) : (ie + (size_t)(c - nu) * EMB);
    return p[lane];
}

// MODE: 0 = first layer (x from ue/ie, acc = own + sum),
//       1 = mid        (x from buf,  acc += sum),
//       2 = last       (x from buf,  acc = (acc+sum)*0.25, no nxt write)
template <int MODE>
__global__ void k_spmm(const int* __restrict__ row_start, const Edge* __restrict__ ecv,
                       const float* __restrict__ x,
                       const float* __restrict__ ue, const float* __restrict__ ie, int nu,
                       float* __restrict__ nxt, float* __restrict__ acc, int n) {
    int wid = (int)(((long)blockIdx.x * blockDim.x + threadIdx.x) >> 6);
    int lane = threadIdx.x & 63;
    if (wid >= n) return;
    int s = row_start[wid];
    int e = row_start[wid + 1];
    float sum = 0.f;
    int j = s;
    for (; j + 4 <= e; j += 4) {
        Edge e0 = ecv[j], e1 = ecv[j + 1], e2 = ecv[j + 2], e3 = ecv[j + 3];
        float x0, x1, x2, x3;
        if (MODE == 0) {
            x0 = gath0(ue, ie, nu, e0.c, lane);
            x1 = gath0(ue, ie, nu, e1.c, lane);
            x2 = gath0(ue, ie, nu, e2.c, lane);
            x3 = gath0(ue, ie, nu, e3.c, lane);
        } else {
            x0 = x[(size_t)e0.c * EMB + lane];
            x1 = x[(size_t)e1.c * EMB + lane];
            x2 = x[(size_t)e2.c * EMB + lane];
            x3 = x[(size_t)e3.c * EMB + lane];
        }
        sum += e0.v * x0 + e1.v * x1 + e2.v * x2 + e3.v * x3;
    }
    for (; j < e; ++j) {
        Edge ed = ecv[j];
        float xv = (MODE == 0) ? gath0(ue, ie, nu, ed.c, lane)
                               : x[(size_t)ed.c * EMB + lane];
        sum += ed.v * xv;
    }
    size_t o = (size_t)wid * EMB + lane;
    if (MODE == 0) {
        float own = gath0(ue, ie, nu, wid, lane);
        nxt[o] = sum;
        acc[o] = own + sum;
    } else if (MODE == 1) {
        nxt[o] = sum;
        acc[o] += sum;
    } else {
        acc[o] = (acc[o] + sum) * 0.25f;
    }
}

// ---------- fallback (R1 atomic path) ----------
__global__ void lgcn_init(const float4* __restrict__ ue, const float4* __restrict__ ie,
                          float4* __restrict__ emb, float4* __restrict__ acc,
                          long nu4, long ni4) {
    long total = nu4 + ni4;
    long stride = (long)gridDim.x * blockDim.x;
    for (long i = (long)blockIdx.x * blockDim.x + threadIdx.x; i < total; i += stride) {
        float4 v = (i < nu4) ? ue[i] : ie[i - nu4];
        emb[i] = v;
        acc[i] = v;
    }
}

__global__ void lgcn_spmm_atomic(const float* __restrict__ vals, const int* __restrict__ rows,
                                 const int* __restrict__ cols, const float* __restrict__ x,
                                 float* __restrict__ y, int ne) {
    long gid = (long)blockIdx.x * blockDim.x + threadIdx.x;
    int e = (int)(gid >> 6);
    int lane = (int)(gid & 63);
    if (e >= ne) return;
    float xv = x[(size_t)cols[e] * EMB + lane];
    atomicAdd(&y[(size_t)rows[e] * EMB + lane], vals[e] * xv);
}

__global__ void lgcn_acc(const float4* __restrict__ src, float4* __restrict__ acc,
                         long n4, float scale) {
    long stride = (long)gridDim.x * blockDim.x;
    for (long i = (long)blockIdx.x * blockDim.x + threadIdx.x; i < n4; i += stride) {
        float4 a = acc[i];
        float4 s = src[i];
        a.x = (a.x + s.x) * scale;
        a.y = (a.y + s.y) * scale;
        a.z = (a.z + s.z) * scale;
        a.w = (a.w + s.w) * scale;
        acc[i] = a;
    }
}

extern "C" void kernel_launch(void* const* d_in, const int* in_sizes, int n_in,
                              void* d_out, int out_size, void* d_ws, size_t ws_size,
                              hipStream_t stream) {
    const float* ue   = (const float*)d_in[0];
    const float* ie   = (const float*)d_in[1];
    const float* vals = (const float*)d_in[2];
    const int*   rows = (const int*)d_in[3];
    const int*   cols = (const int*)d_in[4];

    const int nu = in_sizes[0] / EMB;
    const int ni = in_sizes[1] / EMB;
    const int ne = in_sizes[2];
    const long n = (long)nu + ni;
    const size_t buf_bytes = (size_t)n * EMB * sizeof(float);

    float* acc = (float*)d_out;

    // workspace carve
    char* p = (char*)d_ws;
    float* buf0 = (float*)p;     p += buf_bytes;
    float* buf1 = (float*)p;     p += buf_bytes;
    Edge*  ecv  = (Edge*)p;      p += (size_t)ne * sizeof(Edge);
    int*   row_start = (int*)p;  p += (size_t)(n + 1) * sizeof(int);
    int*   cursor = (int*)p;     p += (size_t)n * sizeof(int);
    int nb = (int)((n + SCAN_ELEMS - 1) / SCAN_ELEMS);
    int*   bsums = (int*)p;      p += (size_t)nb * sizeof(int);
    int*   bexcl = (int*)p;      p += (size_t)nb * sizeof(int);
    size_t needed = (size_t)(p - (char*)d_ws);

    if (needed <= ws_size && nb <= SCAN_TPB) {
        // ---- build CSR ----
        hipMemsetAsync(cursor, 0, (size_t)n * sizeof(int), stream);
        k_hist<<<1024, 256, 0, stream>>>(rows, cursor, ne);
        k_scan1<<<nb, SCAN_TPB, 0, stream>>>(cursor, row_start, bsums, (int)n);
        k_scan2<<<1, SCAN_TPB, 0, stream>>>(bsums, bexcl, nb);
        k_scan3<<<nb, SCAN_TPB, 0, stream>>>(row_start, cursor, bexcl, (int)n, ne);
        k_scatter<<<1024, 256, 0, stream>>>(rows, cols, vals, cursor, ecv, ne);

        // ---- 3 fused SpMM layers ----
        int blocks = (int)((n * 64 + 255) / 256);
        k_spmm<0><<<blocks, 256, 0, stream>>>(row_start, ecv, nullptr, ue, ie, nu,
                                              buf0, acc, (int)n);
        k_spmm<1><<<blocks, 256, 0, stream>>>(row_start, ecv, buf0, ue, ie, nu,
                                              buf1, acc, (int)n);
        k_spmm<2><<<blocks, 256, 0, stream>>>(row_start, ecv, buf1, ue, ie, nu,
                                              nullptr, acc, (int)n);
    } else {
        // ---- fallback: R1 atomic path ----
        const long n4  = n * (EMB / 4);
        const long nu4 = (long)nu * (EMB / 4);
        const long ni4 = (long)ni * (EMB / 4);
        lgcn_init<<<2048, 256, 0, stream>>>((const float4*)ue, (const float4*)ie,
                                            (float4*)buf0, (float4*)acc, nu4, ni4);
        float* cur = buf0;
        float* nxt = buf1;
        for (int l = 0; l < 3; ++l) {
            hipMemsetAsync(nxt, 0, buf_bytes, stream);
            long threads = (long)ne * 64;
            int blk = (int)((threads + 255) / 256);
            lgcn_spmm_atomic<<<blk, 256, 0, stream>>>(vals, rows, cols, cur, nxt, ne);
            float scale = (l == 2) ? 0.25f : 1.0f;
            lgcn_acc<<<2048, 256, 0, stream>>>((const float4*)nxt, (float4*)acc, n4, scale);
            float* t = cur; cur = nxt; nxt = t;
        }
    }
}